// Round 4
// baseline (128.990 us; speedup 1.0000x reference)
//
#include <hip/hip_runtime.h>

#define HID 128

typedef _Float16 f16x8 __attribute__((ext_vector_type(8)));
typedef _Float16 f16x2 __attribute__((ext_vector_type(2)));
typedef float f32x4 __attribute__((ext_vector_type(4)));

union HV { f16x8 v; f16x2 h[4]; };

__device__ __forceinline__ float wshfl(float v, int src)   { return __shfl(v, src, 64); }
__device__ __forceinline__ float wshfl_up(float v, int d)  { return __shfl_up(v, d, 64); }
__device__ __forceinline__ float wshfl_dn(float v, int d)  { return __shfl_down(v, d, 64); }
__device__ __forceinline__ float wshfl_xor(float v, int m) { return __shfl_xor(v, m, 64); }

__device__ __forceinline__ float wave_sum(float v) {
#pragma unroll
    for (int m = 32; m >= 1; m >>= 1) v += wshfl_xor(v, m);
    return v;
}

__device__ __forceinline__ float wave_iscan_add(float v, int lane) {
#pragma unroll
    for (int d = 1; d < 64; d <<= 1) {
        float t = wshfl_up(v, d);
        if (lane >= d) v += t;
    }
    return v;
}

__device__ __forceinline__ float wave_iscan_mul(float v, int lane) {
#pragma unroll
    for (int d = 1; d < 64; d <<= 1) {
        float t = wshfl_up(v, d);
        if (lane >= d) v *= t;
    }
    return v;
}

// convert 8 consecutive floats to f16x8 (two float4 loads)
__device__ __forceinline__ HV cvt8(const float* __restrict__ p) {
    const float4 lo = *(const float4*)p;
    const float4 hi = *(const float4*)(p + 4);
    HV u;
    u.h[0] = f16x2{ (_Float16)lo.x, (_Float16)lo.y };
    u.h[1] = f16x2{ (_Float16)lo.z, (_Float16)lo.w };
    u.h[2] = f16x2{ (_Float16)hi.x, (_Float16)hi.y };
    u.h[3] = f16x2{ (_Float16)hi.z, (_Float16)hi.w };
    return u;
}

// 4-way select by g (register cndmasks, no LDS / shuffles)
__device__ __forceinline__ f32x4 selg(f32x4 a, f32x4 b, f32x4 c, f32x4 d, int g) {
    f32x4 r = a;
    r = (g == 1) ? b : r;
    r = (g == 2) ? c : r;
    r = (g == 3) ? d : r;
    return r;
}

// One 16-sample MLP tile, fully register-resident.
// Lane layout: s16 = lane&15 -> sample column; g = lane>>4 -> k-group
// (lane computes h for hidden = 32c + 8g + e, e=0..7, c=0..3).
// Layer2: 4x mfma_f32_16x16x32_f16, A = W2^T replicated so that every
// row r of D holds out[r&3] -> every lane ends with its column's rgba.
__device__ __forceinline__ f32x4 mlp_tile(float x, float y, float z,
                                          const HV rw0[4], const HV rw1[4],
                                          const HV rw2[4], const HV rb[4],
                                          const f16x8 w2t[4], f32x4 C) {
    const _Float16 xs = (_Float16)x, ys = (_Float16)y, zs = (_Float16)z;
    const f16x2 xp = { xs, xs };
    const f16x2 yp = { ys, ys };
    const f16x2 zp = { zs, zs };
    const f16x2 zero2 = { (_Float16)0, (_Float16)0 };
#pragma unroll
    for (int c = 0; c < 4; ++c) {
        HV hb;
#pragma unroll
        for (int r = 0; r < 4; ++r) {
            f16x2 acc = rw0[c].h[r] * xp + rb[c].h[r];
            acc = rw1[c].h[r] * yp + acc;
            acc = rw2[c].h[r] * zp + acc;
            hb.h[r] = __builtin_elementwise_max(acc, zero2);
        }
        C = __builtin_amdgcn_mfma_f32_16x16x32_f16(w2t[c], hb.v, C, 0, 0, 0);
    }
    return C;
}

extern "C" __global__ void __launch_bounds__(256)
nerf_fused(const float* __restrict__ rays,
           const float* __restrict__ u_coarse,
           const float* __restrict__ u_fine,
           const float* __restrict__ u_jitter,
           const float* __restrict__ W1,
           const float* __restrict__ b1,
           const float* __restrict__ W2,
           const float* __restrict__ b2,
           float* __restrict__ out) {
    const int lane = threadIdx.x & 63;
    const int wv   = threadIdx.x >> 6;   // 0..3, one wave per ray
    const int ray  = (blockIdx.x << 2) + wv;
    const int s16  = lane & 15;
    const int g    = lane >> 4;

    __shared__ float s_cdf[4][65];
    __shared__ float s_zc [4][64];
    __shared__ float s_zf [4][64];
    __shared__ float s_za [4][130];

    // ---- W1/b1 fragments -> registers (f16), once per wave ----
    HV rw0[4], rw1[4], rw2[4], rb[4];
#pragma unroll
    for (int c = 0; c < 4; ++c) {
        const int hid0 = 32 * c + 8 * g;
        rw0[c] = cvt8(W1 + hid0);
        rw1[c] = cvt8(W1 + HID + hid0);
        rw2[c] = cvt8(W1 + 2 * HID + hid0);
        rb [c] = cvt8(b1 + hid0);
    }
    // ---- W2^T fragments (A operand), replicated over row groups ----
    f16x8 w2t[4];
#pragma unroll
    for (int c = 0; c < 4; ++c) {
        HV u;
#pragma unroll
        for (int r = 0; r < 4; ++r) {
            const int k0 = 32 * c + 8 * g + 2 * r;
            const float a0 = W2[k0 * 4 + (s16 & 3)];
            const float a1 = W2[(k0 + 1) * 4 + (s16 & 3)];
            u.h[r] = f16x2{ (_Float16)a0, (_Float16)a1 };
        }
        w2t[c] = u.v;
    }
    f32x4 cini;
    cini[0] = b2[0]; cini[1] = b2[1]; cini[2] = b2[2]; cini[3] = b2[3];

    // ---- ray data (wave-uniform) ----
    const float* rp = rays + ray * 8;
    const float ox = rp[0], oy = rp[1], oz = rp[2];
    const float dx = rp[3], dy = rp[4], dz = rp[5];
    const float nearv = rp[6], farv = rp[7];

    // ================= coarse sampling =================
    const float uc = u_coarse[(ray << 6) + lane];
    const float zsv = ((float)lane + uc) * 0.015625f;
    const float zc = nearv * (1.0f - zsv) + farv * zsv;
    s_zc[wv][lane] = zc;

    // ---- coarse MLP: 4 tiles of 16 samples, outputs stay in registers ----
    float zt[4];
#pragma unroll
    for (int t = 0; t < 4; ++t) zt[t] = s_zc[wv][t * 16 + s16];
    f32x4 C0, C1, C2, C3;
    {
        C0 = mlp_tile(fmaf(zt[0], dx, ox), fmaf(zt[0], dy, oy), fmaf(zt[0], dz, oz), rw0, rw1, rw2, rb, w2t, cini);
        C1 = mlp_tile(fmaf(zt[1], dx, ox), fmaf(zt[1], dy, oy), fmaf(zt[1], dz, oz), rw0, rw1, rw2, rb, w2t, cini);
        C2 = mlp_tile(fmaf(zt[2], dx, ox), fmaf(zt[2], dy, oy), fmaf(zt[2], dz, oz), rw0, rw1, rw2, rb, w2t, cini);
        C3 = mlp_tile(fmaf(zt[3], dx, ox), fmaf(zt[3], dy, oy), fmaf(zt[3], dz, oz), rw0, rw1, rw2, rb, w2t, cini);
    }
    const f32x4 cv = selg(C0, C1, C2, C3, g);   // lane j holds rgba of coarse sample j

    // ---- coarse composite ----
    {
        const float znext = wshfl_dn(zc, 1);
        const float delta = (lane == 63) ? (farv - zc) : (znext - zc);
        const float alpha = 1.0f - __expf(-delta * fmaxf(cv[3], 0.0f));

        float f  = 1.0f - alpha + 1e-10f;
        float ip = wave_iscan_mul(f, lane);
        float Te = wshfl_up(ip, 1);
        if (lane == 0) Te = 1.0f;
        const float w = alpha * Te;

        const float rc = wave_sum(w * cv[0]);
        const float gc = wave_sum(w * cv[1]);
        const float bc = wave_sum(w * cv[2]);
        const float dc = wave_sum(w * zc);

        float wp = w + 1e-5f;
        float cs = wave_iscan_add(wp, lane);
        float total = wshfl(cs, 63);
        if (lane == 0) s_cdf[wv][0] = 0.0f;
        s_cdf[wv][lane + 1] = cs / total;

        if (lane == 0) {
            float4* op = (float4*)(out + ray * 8);
            op[0] = make_float4(rc, gc, bc, dc);
        }
    }

    // ================= fine sampling =================
    const float uf = u_fine[(ray << 6) + lane];
    const float uj = u_jitter[(ray << 6) + lane];

    int lo = 0, hi = 65;            // upper_bound over cdf[0..64]
#pragma unroll
    for (int it = 0; it < 7; ++it) {
        if (lo < hi) {
            int mid = (lo + hi) >> 1;
            if (s_cdf[wv][mid] <= uf) lo = mid + 1; else hi = mid;
        }
    }
    const float ind = fmaxf((float)lo - 1.0f, 0.0f);
    const float zfs = (ind + uj) * 0.015625f;
    const float zfv = nearv * (1.0f - zfs) + farv * zfs;

    // ---- bitonic sort of fine z across the wave (ascending) ----
    float v = zfv;
#pragma unroll
    for (int k = 2; k <= 64; k <<= 1) {
#pragma unroll
        for (int j = k >> 1; j > 0; j >>= 1) {
            float other = wshfl_xor(v, j);
            bool asc = ((lane & k) == 0);
            bool low = ((lane & j) == 0);
            float mn = fminf(v, other), mx = fmaxf(v, other);
            v = (asc == low) ? mn : mx;
        }
    }
    s_zf[wv][lane] = v;

    // ---- merge ranks: z_all = stable-sort(concat(zc, zf)) ----
    int lof = 0, hif = 64;          // lower_bound of zc in zf_sorted
#pragma unroll
    for (int it = 0; it < 7; ++it) {
        if (lof < hif) {
            int mid = (lof + hif) >> 1;
            if (s_zf[wv][mid] < zc) lof = mid + 1; else hif = mid;
        }
    }
    int loc = 0, hic = 64;          // upper_bound of v in zc
#pragma unroll
    for (int it = 0; it < 7; ++it) {
        if (loc < hic) {
            int mid = (loc + hic) >> 1;
            if (s_zc[wv][mid] <= v) loc = mid + 1; else hic = mid;
        }
    }
    s_za[wv][lane + lof] = zc;
    s_za[wv][lane + loc] = v;

    // ---- fine MLP: 8 tiles of 16 samples; lane j ends holding rgba of
    //      samples j (vA, tiles 0-3) and j+64 (vB, tiles 4-7) ----
    float zu[8];
#pragma unroll
    for (int t = 0; t < 8; ++t) zu[t] = s_za[wv][t * 16 + s16];

    f32x4 vA, vB;
    {
        f32x4 F0 = mlp_tile(fmaf(zu[0], dx, ox), fmaf(zu[0], dy, oy), fmaf(zu[0], dz, oz), rw0, rw1, rw2, rb, w2t, cini);
        f32x4 F1 = mlp_tile(fmaf(zu[1], dx, ox), fmaf(zu[1], dy, oy), fmaf(zu[1], dz, oz), rw0, rw1, rw2, rb, w2t, cini);
        f32x4 F2 = mlp_tile(fmaf(zu[2], dx, ox), fmaf(zu[2], dy, oy), fmaf(zu[2], dz, oz), rw0, rw1, rw2, rb, w2t, cini);
        f32x4 F3 = mlp_tile(fmaf(zu[3], dx, ox), fmaf(zu[3], dy, oy), fmaf(zu[3], dz, oz), rw0, rw1, rw2, rb, w2t, cini);
        vA = selg(F0, F1, F2, F3, g);
    }
    {
        f32x4 F4 = mlp_tile(fmaf(zu[4], dx, ox), fmaf(zu[4], dy, oy), fmaf(zu[4], dz, oz), rw0, rw1, rw2, rb, w2t, cini);
        f32x4 F5 = mlp_tile(fmaf(zu[5], dx, ox), fmaf(zu[5], dy, oy), fmaf(zu[5], dz, oz), rw0, rw1, rw2, rb, w2t, cini);
        f32x4 F6 = mlp_tile(fmaf(zu[6], dx, ox), fmaf(zu[6], dy, oy), fmaf(zu[6], dz, oz), rw0, rw1, rw2, rb, w2t, cini);
        f32x4 F7 = mlp_tile(fmaf(zu[7], dx, ox), fmaf(zu[7], dy, oy), fmaf(zu[7], dz, oz), rw0, rw1, rw2, rb, w2t, cini);
        vB = selg(F4, F5, F6, F7, g);
    }

    // ---- fine composite: lane j handles samples j and j+64 ----
    {
        const float zA = s_za[wv][lane];
        const float zB = s_za[wv][lane + 64];

        const float zA1 = wshfl_dn(zA, 1);
        const float zB0 = wshfl(zB, 0);      // z[64]
        const float zB1 = wshfl_dn(zB, 1);
        const float dA = (lane == 63) ? (zB0 - zA) : (zA1 - zA);
        const float dB = (lane == 63) ? (farv - zB) : (zB1 - zB);

        const float aA = 1.0f - __expf(-dA * fmaxf(vA[3], 0.0f));
        const float aB = 1.0f - __expf(-dB * fmaxf(vB[3], 0.0f));
        const float fA = 1.0f - aA + 1e-10f;
        const float fB = 1.0f - aB + 1e-10f;

        float ipA = wave_iscan_mul(fA, lane);
        float TA  = wshfl_up(ipA, 1);
        if (lane == 0) TA = 1.0f;
        const float wA = aA * TA;

        const float Pall = wshfl(ipA, 63);   // prod of fA over first 64
        float ipB = wave_iscan_mul(fB, lane);
        float TBp = wshfl_up(ipB, 1);
        if (lane == 0) TBp = 1.0f;
        const float wB = aB * Pall * TBp;

        const float rf = wave_sum(fmaf(wA, vA[0], wB * vB[0]));
        const float gf = wave_sum(fmaf(wA, vA[1], wB * vB[1]));
        const float bf = wave_sum(fmaf(wA, vA[2], wB * vB[2]));
        const float df = wave_sum(fmaf(wA, zA, wB * zB));

        if (lane == 0) {
            float4* op = (float4*)(out + ray * 8);
            op[1] = make_float4(rf, gf, bf, df);
        }
    }
}

extern "C" void kernel_launch(void* const* d_in, const int* in_sizes, int n_in,
                              void* d_out, int out_size, void* d_ws, size_t ws_size,
                              hipStream_t stream) {
    const float* rays = (const float*)d_in[0];
    const float* uc   = (const float*)d_in[1];
    const float* uf   = (const float*)d_in[2];
    const float* uj   = (const float*)d_in[3];
    const float* W1   = (const float*)d_in[4];
    const float* b1   = (const float*)d_in[5];
    const float* W2   = (const float*)d_in[6];
    const float* b2   = (const float*)d_in[7];
    float* o          = (float*)d_out;

    const int R = in_sizes[0] / 8;
    dim3 grid(R / 4), block(256);
    hipLaunchKernelGGL(nerf_fused, grid, block, 0, stream,
                       rays, uc, uf, uj, W1, b1, W2, b2, o);
}

// Round 7
// 127.837 us; speedup vs baseline: 1.0090x; 1.0090x over previous
//
#include <hip/hip_runtime.h>

#define HID 128

typedef _Float16 f16x8 __attribute__((ext_vector_type(8)));
typedef _Float16 f16x2 __attribute__((ext_vector_type(2)));
typedef float f32x4 __attribute__((ext_vector_type(4)));

union HV { f16x8 v; f16x2 h[4]; };

// ---------------- DPP / cross-lane primitives (no ds_bpermute) ----------------
// update_dpp(old, src, ctrl, row_mask, bank_mask, bound_ctrl=false):
// invalid/masked lanes keep `old` (the op identity for scans).
template <int CTRL, int RM = 0xF, int BM = 0xF>
__device__ __forceinline__ float updf(float old, float src) {
    int o = __builtin_bit_cast(int, old);
    int s = __builtin_bit_cast(int, src);
    int r = __builtin_amdgcn_update_dpp(o, s, CTRL, RM, BM, false);
    return __builtin_bit_cast(float, r);
}

__device__ __forceinline__ float readlanef(float v, int l) {
    return __builtin_bit_cast(float, __builtin_amdgcn_readlane(__builtin_bit_cast(int, v), l));
}

// inclusive prefix-sum across 64 lanes, pure DPP (LLVM AtomicOptimizer idiom)
__device__ __forceinline__ float dscan_add(float v) {
    v += updf<0x111>(0.0f, v);              // row_shr:1
    v += updf<0x112>(0.0f, v);              // row_shr:2
    v += updf<0x114>(0.0f, v);              // row_shr:4
    v += updf<0x118>(0.0f, v);              // row_shr:8
    v += updf<0x142, 0xA>(0.0f, v);         // row_bcast:15 -> rows 1,3
    v += updf<0x143, 0xC>(0.0f, v);         // row_bcast:31 -> rows 2,3
    return v;
}

// inclusive prefix-product across 64 lanes
__device__ __forceinline__ float dscan_mul(float v) {
    v *= updf<0x111>(1.0f, v);
    v *= updf<0x112>(1.0f, v);
    v *= updf<0x114>(1.0f, v);
    v *= updf<0x118>(1.0f, v);
    v *= updf<0x142, 0xA>(1.0f, v);
    v *= updf<0x143, 0xC>(1.0f, v);
    return v;
}

// exclusive from inclusive: shift whole wave right by 1, lane0 = identity
__device__ __forceinline__ float dexcl(float incl, float ident) {
    return updf<0x138>(ident, incl);        // wave_shr:1
}
// lane i <- value of lane i+1 (lane 63 keeps old)
__device__ __forceinline__ float dnext(float v) {
    return updf<0x130>(0.0f, v);            // wave_shl:1
}

template <int IMM>
__device__ __forceinline__ float swzf(float v) {
    return __builtin_bit_cast(float,
        __builtin_amdgcn_ds_swizzle(__builtin_bit_cast(int, v), IMM));
}

// butterfly partner at xor-distance M (compile-time)
template <int M>
__device__ __forceinline__ float bx(float v) {
    if constexpr (M == 1)       return updf<0xB1>(v, v);        // quad_perm [1,0,3,2]
    else if constexpr (M == 2)  return updf<0x4E>(v, v);        // quad_perm [2,3,0,1]
    else if constexpr (M == 4)  return swzf<0x101F>(v);         // ds_swizzle xor4
    else if constexpr (M == 8)  return swzf<0x201F>(v);         // ds_swizzle xor8
    else if constexpr (M == 16) return swzf<0x401F>(v);         // ds_swizzle xor16
    else                        return __shfl_xor(v, 32, 64);   // cross-half
}

// convert 8 consecutive floats to f16x8 (two float4 loads)
__device__ __forceinline__ HV cvt8(const float* __restrict__ p) {
    const float4 lo = *(const float4*)p;
    const float4 hi = *(const float4*)(p + 4);
    HV u;
    u.h[0] = f16x2{ (_Float16)lo.x, (_Float16)lo.y };
    u.h[1] = f16x2{ (_Float16)lo.z, (_Float16)lo.w };
    u.h[2] = f16x2{ (_Float16)hi.x, (_Float16)hi.y };
    u.h[3] = f16x2{ (_Float16)hi.z, (_Float16)hi.w };
    return u;
}

// 4-way select by g (register cndmasks)
__device__ __forceinline__ f32x4 selg(f32x4 a, f32x4 b, f32x4 c, f32x4 d, int g) {
    f32x4 r = a;
    r = (g == 1) ? b : r;
    r = (g == 2) ? c : r;
    r = (g == 3) ? d : r;
    return r;
}

// One 16-sample MLP tile, fully register-resident (see round-3 notes).
__device__ __forceinline__ f32x4 mlp_tile(float x, float y, float z,
                                          const HV rw0[4], const HV rw1[4],
                                          const HV rw2[4], const HV rb[4],
                                          const f16x8 w2t[4], f32x4 C) {
    const _Float16 xs = (_Float16)x, ys = (_Float16)y, zs = (_Float16)z;
    const f16x2 xp = { xs, xs };
    const f16x2 yp = { ys, ys };
    const f16x2 zp = { zs, zs };
    const f16x2 zero2 = { (_Float16)0, (_Float16)0 };
#pragma unroll
    for (int c = 0; c < 4; ++c) {
        HV hb;
#pragma unroll
        for (int r = 0; r < 4; ++r) {
            f16x2 acc = rw0[c].h[r] * xp + rb[c].h[r];
            acc = rw1[c].h[r] * yp + acc;
            acc = rw2[c].h[r] * zp + acc;
            hb.h[r] = __builtin_elementwise_max(acc, zero2);
        }
        C = __builtin_amdgcn_mfma_f32_16x16x32_f16(w2t[c], hb.v, C, 0, 0, 0);
    }
    return C;
}

extern "C" __global__ void __launch_bounds__(256)
nerf_fused(const float* __restrict__ rays,
           const float* __restrict__ u_coarse,
           const float* __restrict__ u_fine,
           const float* __restrict__ u_jitter,
           const float* __restrict__ W1,
           const float* __restrict__ b1,
           const float* __restrict__ W2,
           const float* __restrict__ b2,
           float* __restrict__ out) {
    const int lane = threadIdx.x & 63;
    const int wv   = threadIdx.x >> 6;   // 0..3, one wave per ray
    const int ray  = (blockIdx.x << 2) + wv;
    const int s16  = lane & 15;
    const int g    = lane >> 4;

    __shared__ float s_cdf[4][65];
    __shared__ float s_zc [4][64];
    __shared__ float s_zf [4][64];
    __shared__ float s_za [4][130];

    // ---- W1/b1 fragments -> registers (f16), once per wave ----
    HV rw0[4], rw1[4], rw2[4], rb[4];
#pragma unroll
    for (int c = 0; c < 4; ++c) {
        const int hid0 = 32 * c + 8 * g;
        rw0[c] = cvt8(W1 + hid0);
        rw1[c] = cvt8(W1 + HID + hid0);
        rw2[c] = cvt8(W1 + 2 * HID + hid0);
        rb [c] = cvt8(b1 + hid0);
    }
    // ---- W2^T fragments (A operand), replicated over row groups ----
    f16x8 w2t[4];
#pragma unroll
    for (int c = 0; c < 4; ++c) {
        HV u;
#pragma unroll
        for (int r = 0; r < 4; ++r) {
            const int k0 = 32 * c + 8 * g + 2 * r;
            const float a0 = W2[k0 * 4 + (s16 & 3)];
            const float a1 = W2[(k0 + 1) * 4 + (s16 & 3)];
            u.h[r] = f16x2{ (_Float16)a0, (_Float16)a1 };
        }
        w2t[c] = u.v;
    }
    f32x4 cini;
    cini[0] = b2[0]; cini[1] = b2[1]; cini[2] = b2[2]; cini[3] = b2[3];

    // ---- ray data (wave-uniform) ----
    const float* rp = rays + ray * 8;
    const float ox = rp[0], oy = rp[1], oz = rp[2];
    const float dx = rp[3], dy = rp[4], dz = rp[5];
    const float nearv = rp[6], farv = rp[7];

    // ================= coarse sampling =================
    const float uc = u_coarse[(ray << 6) + lane];
    const float zsv = ((float)lane + uc) * 0.015625f;
    const float zc = nearv * (1.0f - zsv) + farv * zsv;
    s_zc[wv][lane] = zc;

    // ---- coarse MLP: 4 tiles of 16 samples, outputs stay in registers ----
    float zt[4];
#pragma unroll
    for (int t = 0; t < 4; ++t) zt[t] = s_zc[wv][t * 16 + s16];
    f32x4 C0, C1, C2, C3;
    {
        C0 = mlp_tile(fmaf(zt[0], dx, ox), fmaf(zt[0], dy, oy), fmaf(zt[0], dz, oz), rw0, rw1, rw2, rb, w2t, cini);
        C1 = mlp_tile(fmaf(zt[1], dx, ox), fmaf(zt[1], dy, oy), fmaf(zt[1], dz, oz), rw0, rw1, rw2, rb, w2t, cini);
        C2 = mlp_tile(fmaf(zt[2], dx, ox), fmaf(zt[2], dy, oy), fmaf(zt[2], dz, oz), rw0, rw1, rw2, rb, w2t, cini);
        C3 = mlp_tile(fmaf(zt[3], dx, ox), fmaf(zt[3], dy, oy), fmaf(zt[3], dz, oz), rw0, rw1, rw2, rb, w2t, cini);
    }
    const f32x4 cv = selg(C0, C1, C2, C3, g);   // lane j holds rgba of coarse sample j

    // ---- coarse composite (all cross-lane via DPP) ----
    {
        const float znext = dnext(zc);
        const float delta = (lane == 63) ? (farv - zc) : (znext - zc);
        const float alpha = 1.0f - __expf(-delta * fmaxf(cv[3], 0.0f));

        const float f  = 1.0f - alpha + 1e-10f;
        const float ip = dscan_mul(f);
        const float Te = dexcl(ip, 1.0f);
        const float w  = alpha * Te;

        const float rS = dscan_add(w * cv[0]);
        const float gS = dscan_add(w * cv[1]);
        const float bS = dscan_add(w * cv[2]);
        const float dS = dscan_add(w * zc);

        const float wp = w + 1e-5f;
        const float cs = dscan_add(wp);
        const float total = readlanef(cs, 63);
        if (lane == 0) s_cdf[wv][0] = 0.0f;
        s_cdf[wv][lane + 1] = cs / total;

        if (lane == 63) {
            float4* op = (float4*)(out + ray * 8);
            op[0] = make_float4(rS, gS, bS, dS);
        }
    }

    // ================= fine sampling =================
    const float uf = u_fine[(ray << 6) + lane];
    const float uj = u_jitter[(ray << 6) + lane];

    int lo = 0, hi = 65;            // upper_bound over cdf[0..64]
#pragma unroll
    for (int it = 0; it < 7; ++it) {
        if (lo < hi) {
            int mid = (lo + hi) >> 1;
            if (s_cdf[wv][mid] <= uf) lo = mid + 1; else hi = mid;
        }
    }
    const float ind = fmaxf((float)lo - 1.0f, 0.0f);
    const float zfs = (ind + uj) * 0.015625f;
    const float zfv = nearv * (1.0f - zfs) + farv * zfs;

    // ---- bitonic sort of fine z across the wave (ascending) ----
    float v = zfv;
#define BSTEP(K, J) { float o = bx<J>(v);                               \
                      bool asc = ((lane & K) == 0);                     \
                      bool low = ((lane & J) == 0);                     \
                      float mn = fminf(v, o), mx = fmaxf(v, o);         \
                      v = (asc == low) ? mn : mx; }
    BSTEP(2, 1)
    BSTEP(4, 2)  BSTEP(4, 1)
    BSTEP(8, 4)  BSTEP(8, 2)  BSTEP(8, 1)
    BSTEP(16, 8) BSTEP(16, 4) BSTEP(16, 2) BSTEP(16, 1)
    BSTEP(32, 16) BSTEP(32, 8) BSTEP(32, 4) BSTEP(32, 2) BSTEP(32, 1)
    BSTEP(64, 32) BSTEP(64, 16) BSTEP(64, 8) BSTEP(64, 4) BSTEP(64, 2) BSTEP(64, 1)
#undef BSTEP
    s_zf[wv][lane] = v;

    // ---- merge ranks: z_all = stable-sort(concat(zc, zf)) ----
    int lof = 0, hif = 64;          // lower_bound of zc in zf_sorted
#pragma unroll
    for (int it = 0; it < 7; ++it) {
        if (lof < hif) {
            int mid = (lof + hif) >> 1;
            if (s_zf[wv][mid] < zc) lof = mid + 1; else hif = mid;
        }
    }
    int loc = 0, hic = 64;          // upper_bound of v in zc
#pragma unroll
    for (int it = 0; it < 7; ++it) {
        if (loc < hic) {
            int mid = (loc + hic) >> 1;
            if (s_zc[wv][mid] <= v) loc = mid + 1; else hic = mid;
        }
    }
    s_za[wv][lane + lof] = zc;
    s_za[wv][lane + loc] = v;

    // ---- fine MLP: 8 tiles of 16 samples; lane j ends holding rgba of
    //      samples j (vA, tiles 0-3) and j+64 (vB, tiles 4-7) ----
    float zu[8];
#pragma unroll
    for (int t = 0; t < 8; ++t) zu[t] = s_za[wv][t * 16 + s16];

    f32x4 vA, vB;
    {
        f32x4 F0 = mlp_tile(fmaf(zu[0], dx, ox), fmaf(zu[0], dy, oy), fmaf(zu[0], dz, oz), rw0, rw1, rw2, rb, w2t, cini);
        f32x4 F1 = mlp_tile(fmaf(zu[1], dx, ox), fmaf(zu[1], dy, oy), fmaf(zu[1], dz, oz), rw0, rw1, rw2, rb, w2t, cini);
        f32x4 F2 = mlp_tile(fmaf(zu[2], dx, ox), fmaf(zu[2], dy, oy), fmaf(zu[2], dz, oz), rw0, rw1, rw2, rb, w2t, cini);
        f32x4 F3 = mlp_tile(fmaf(zu[3], dx, ox), fmaf(zu[3], dy, oy), fmaf(zu[3], dz, oz), rw0, rw1, rw2, rb, w2t, cini);
        vA = selg(F0, F1, F2, F3, g);
    }
    {
        f32x4 F4 = mlp_tile(fmaf(zu[4], dx, ox), fmaf(zu[4], dy, oy), fmaf(zu[4], dz, oz), rw0, rw1, rw2, rb, w2t, cini);
        f32x4 F5 = mlp_tile(fmaf(zu[5], dx, ox), fmaf(zu[5], dy, oy), fmaf(zu[5], dz, oz), rw0, rw1, rw2, rb, w2t, cini);
        f32x4 F6 = mlp_tile(fmaf(zu[6], dx, ox), fmaf(zu[6], dy, oy), fmaf(zu[6], dz, oz), rw0, rw1, rw2, rb, w2t, cini);
        f32x4 F7 = mlp_tile(fmaf(zu[7], dx, ox), fmaf(zu[7], dy, oy), fmaf(zu[7], dz, oz), rw0, rw1, rw2, rb, w2t, cini);
        vB = selg(F4, F5, F6, F7, g);
    }

    // ---- fine composite: lane j handles samples j and j+64 ----
    {
        const float zA = s_za[wv][lane];
        const float zB = s_za[wv][lane + 64];

        const float zA1 = dnext(zA);
        const float zB1 = dnext(zB);
        const float zB0 = readlanef(zB, 0);      // z[64]
        const float dA = (lane == 63) ? (zB0 - zA) : (zA1 - zA);
        const float dB = (lane == 63) ? (farv - zB) : (zB1 - zB);

        const float aA = 1.0f - __expf(-dA * fmaxf(vA[3], 0.0f));
        const float aB = 1.0f - __expf(-dB * fmaxf(vB[3], 0.0f));
        const float fA = 1.0f - aA + 1e-10f;
        const float fB = 1.0f - aB + 1e-10f;

        const float ipA = dscan_mul(fA);
        const float TA  = dexcl(ipA, 1.0f);
        const float wA  = aA * TA;

        const float Pall = readlanef(ipA, 63);   // prod of fA over first 64
        const float ipB = dscan_mul(fB);
        const float TBp = dexcl(ipB, 1.0f);
        const float wB  = aB * Pall * TBp;

        const float rS = dscan_add(fmaf(wA, vA[0], wB * vB[0]));
        const float gS = dscan_add(fmaf(wA, vA[1], wB * vB[1]));
        const float bS = dscan_add(fmaf(wA, vA[2], wB * vB[2]));
        const float dS = dscan_add(fmaf(wA, zA, wB * zB));

        if (lane == 63) {
            float4* op = (float4*)(out + ray * 8);
            op[1] = make_float4(rS, gS, bS, dS);
        }
    }
}

extern "C" void kernel_launch(void* const* d_in, const int* in_sizes, int n_in,
                              void* d_out, int out_size, void* d_ws, size_t ws_size,
                              hipStream_t stream) {
    const float* rays = (const float*)d_in[0];
    const float* uc   = (const float*)d_in[1];
    const float* uf   = (const float*)d_in[2];
    const float* uj   = (const float*)d_in[3];
    const float* W1   = (const float*)d_in[4];
    const float* b1   = (const float*)d_in[5];
    const float* W2   = (const float*)d_in[6];
    const float* b2   = (const float*)d_in[7];
    float* o          = (float*)d_out;

    const int R = in_sizes[0] / 8;
    dim3 grid(R / 4), block(256);
    hipLaunchKernelGGL(nerf_fused, grid, block, 0, stream,
                       rays, uc, uf, uj, W1, b1, W2, b2, o);
}